// Round 10
// baseline (233.664 us; speedup 1.0000x reference)
//
#include <hip/hip_runtime.h>
#include <math.h>

// LayerNorm(Re(FFT(x, axis=-1))), x: (B=4, N=4096, C=2048) fp32.
// One 256-thread block per PAIR of rows: z = x_even + i*x_odd.
// WAVE-DECOUPLED DIT: 2048 = 4 x 512. Wave w owns the 512-pt FFT of
// z_w[m] = z[4m+w] (radix-8^3, Stockham, wave-private LDS segment, exchanges
// synced with lgkmcnt only -- NO block barrier). ONE barrier publishes the
// four spectra; per-thread radix-4 combine X[k] = sum_l W_2048^{l*sig} X_l[sig]
// reproduces the Z[u] @ k=sig+256u layout, so the verified shfl_xor(.,1)
// conjugate untangle + LDS-repartitioned float4 epilogue are reused verbatim.
// Block barriers: 7 -> 2. Stage-C twiddles are unity (free).
// History: twiddle-table(+21us, reverted), NT stores(+17% writes, reverted),
// ILP-2(-39% occ, reverted), coalesced epilogue (neutral, kept).
// Padded LDS phys(i) = i + (i>>3): 18.4 KB/block -> 8 blocks/CU.

#define TPB 256
#define CD  2048

// Same-wave LDS fence: DS ops of one wave execute in order; this drains them
// and (via the memory clobber) stops the compiler reordering across it.
#define WAVE_SYNC() asm volatile("s_waitcnt lgkmcnt(0)" ::: "memory")

__device__ __forceinline__ float2 cadd(float2 a, float2 b){ return make_float2(a.x+b.x, a.y+b.y); }
__device__ __forceinline__ float2 csub(float2 a, float2 b){ return make_float2(a.x-b.x, a.y-b.y); }

// y_r = sum_k z_k * exp(-2*pi*i*k*r/8), natural output order.
__device__ __forceinline__ void dft8(const float2* z, float2* y)
{
    const float C8 = 0.70710678118654752440f;  // sqrt(2)/2
    float2 a0=cadd(z[0],z[4]), a1=cadd(z[1],z[5]), a2=cadd(z[2],z[6]), a3=cadd(z[3],z[7]);
    float2 b0=csub(z[0],z[4]), b1=csub(z[1],z[5]), b2=csub(z[2],z[6]), b3=csub(z[3],z[7]);
    float2 t1=make_float2(C8*(b1.x+b1.y), C8*(b1.y-b1.x));     // b1 * w8^1
    float2 t2=make_float2(b2.y, -b2.x);                        // b2 * w8^2 = -i
    float2 t3=make_float2(C8*(b3.y-b3.x), -C8*(b3.x+b3.y));    // b3 * w8^3
    {   // even outputs = DFT4(a0..a3)
        float pr=a0.x+a2.x, pi=a0.y+a2.y, mr=a0.x-a2.x, mi=a0.y-a2.y;
        float qr=a1.x+a3.x, qi=a1.y+a3.y, nr=a1.x-a3.x, ni=a1.y-a3.y;
        y[0]=make_float2(pr+qr,pi+qi); y[2]=make_float2(mr+ni,mi-nr);
        y[4]=make_float2(pr-qr,pi-qi); y[6]=make_float2(mr-ni,mi+nr);
    }
    {   // odd outputs = DFT4(b0,t1,t2,t3)
        float pr=b0.x+t2.x, pi=b0.y+t2.y, mr=b0.x-t2.x, mi=b0.y-t2.y;
        float qr=t1.x+t3.x, qi=t1.y+t3.y, nr=t1.x-t3.x, ni=t1.y-t3.y;
        y[1]=make_float2(pr+qr,pi+qi); y[3]=make_float2(mr+ni,mi-nr);
        y[5]=make_float2(pr-qr,pi-qi); y[7]=make_float2(mr-ni,mi+nr);
    }
}

// cw[r],sw[r] = cos/sin(th1*r), r=0..7; tree-structured (dep depth 3).
__device__ __forceinline__ void make_tw(float th1, float* cw, float* sw)
{
    float s1, c1;
    __sincosf(th1, &s1, &c1);
    cw[0]=1.f;                       sw[0]=0.f;
    cw[1]=c1;                        sw[1]=s1;
    cw[2]=c1*c1-s1*s1;               sw[2]=2.f*c1*s1;
    cw[4]=cw[2]*cw[2]-sw[2]*sw[2];   sw[4]=2.f*cw[2]*sw[2];
    cw[3]=c1*cw[2]-s1*sw[2];         sw[3]=s1*cw[2]+c1*sw[2];
    cw[5]=c1*cw[4]-s1*sw[4];         sw[5]=s1*cw[4]+c1*sw[4];
    cw[6]=cw[2]*cw[4]-sw[2]*sw[4];   sw[6]=sw[2]*cw[4]+cw[2]*sw[4];
    cw[7]=cw[3]*cw[4]-sw[3]*sw[4];   sw[7]=sw[3]*cw[4]+cw[3]*sw[4];
}

// Stockham store with twiddles w_r = (cw[r], sw[r]).
template<int OFFM>
__device__ __forceinline__ void r8_store(float2* Lw, const float2* y,
                                         const float* cw, const float* sw)
{
    Lw[0] = y[0];
#pragma unroll
    for (int r = 1; r < 8; ++r)
        Lw[OFFM*r] = make_float2(cw[r]*y[r].x - sw[r]*y[r].y,
                                 cw[r]*y[r].y + sw[r]*y[r].x);
}

__global__ __launch_bounds__(TPB, 8) void fourier_ln_kernel(
    const float* __restrict__ x,
    const float* __restrict__ gamma,
    const float* __restrict__ beta,
    float* __restrict__ out)
{
    __shared__ float2 L[2304];    // 4 x 576 wave segments; phys(i) = i + (i>>3)
    __shared__ float rmem[16];    // cross-wave reduction scratch

    const int t  = threadIdx.x;
    const int e  = t & 63;        // lane
    const int w  = t >> 6;        // wave = residue class l
    const int e8 = e >> 3;
    const long long row0 = 2LL * (long long)blockIdx.x;
    const float* __restrict__ x0 = x + row0 * CD;
    const float* __restrict__ x1 = x0 + CD;

    // DIT split: wave w owns z_w[m] = z[4m+w]; lane e holds m = e + 64r.
    // Global index n = 4e + 256r + w (stride-16B loads; sibling waves of the
    // block consume the rest of each cache line).
    float2 z[8], y[8];
#pragma unroll
    for (int r = 0; r < 8; ++r) {
        const int n = 4*e + 256*r + w;
        z[r] = make_float2(x0[n], x1[n]);
    }

    float cw[8], sw[8];
    float2* const Lw = L + 576*w;             // wave-private segment

    // ---- Wave-private 512-pt FFT: radix-8 stages S=1,8,64 (Stockham) ----
    // Stage A (S=1): twiddle W_512^{e*r}; logical 8e+r -> phys 9e+r.
    make_tw(-1.22718463030851329843e-2f * (float)e, cw, sw);   // -2pi/512 * e
    dft8(z, y);
    r8_store<1>(Lw + 9*e, y, cw, sw);
    WAVE_SYNC();

    // Stage B (S=8): read logical e+64k (phys e+e8+72k); q=e&7, p=e8;
    // twiddle W_64^{p*r}; write logical q+64p+8r -> phys q+72p+9r.
    {
        const float2* Lr = Lw + e + e8;
#pragma unroll
        for (int k = 0; k < 8; ++k) z[k] = Lr[72*k];
    }
    make_tw(-9.81747704246810387019e-2f * (float)e8, cw, sw);  // -2pi/64 * p
    dft8(z, y);
    r8_store<9>(Lw + (e & 7) + 72*e8, y, cw, sw);
    WAVE_SYNC();

    // Stage C (S=64): twiddle-free (W_8^0). Read logical e+64k, write the
    // SAME slots (lane-private rewrite): X_w[e+64r] at phys e+e8+72r.
    {
        float2* Lr = Lw + e + e8;
#pragma unroll
        for (int k = 0; k < 8; ++k) z[k] = Lr[72*k];
        dft8(z, y);
#pragma unroll
        for (int r = 0; r < 8; ++r) Lr[72*r] = y[r];
    }
    __syncthreads();   // publish the four 512-spectra (barrier #1 of 2)

    // ---- Combine: X[k] = sum_l W_2048^{l*k} X_l[k mod 512] ----
    // sigma: even lane of a pair takes sig=u (u=t>>1), odd takes 256-u
    // (u==0 -> 128) so partners {sig, 256-sig} are lane-adjacent.
    const int u   = t >> 1;
    const int sig = (t & 1) ? ((u == 0) ? 128 : 256 - u) : u;
    const int po  = sig + (sig >> 3);         // phys(sig) within a segment

    float2 XA[4], XB[4];                      // X_l[sig], X_l[sig+256]
#pragma unroll
    for (int l = 0; l < 4; ++l) {
        XA[l] = L[576*l + po];
        XB[l] = L[576*l + po + 288];          // phys(sig+256) = po + 288
    }

    // w_l = W_2048^{l*sig}, l=1..3 (tree powers).
    float c1, s1;
    __sincosf(-3.06796157577128245943e-3f * (float)sig, &s1, &c1);
    const float c2 = c1*c1 - s1*s1, s2 = 2.f*c1*s1;
    const float c3 = c1*c2 - s1*s2, s3 = s1*c2 + c1*s2;
    const float C8 = 0.70710678118654752440f;

    float2 Z[8];   // Z[u] = X[sig + 256u]
    {   // j = sig: T_l = w_l * XA[l]; DFT4 over l -> u = 0,2,4,6
        float2 T0 = XA[0];
        float2 T1 = make_float2(c1*XA[1].x - s1*XA[1].y, c1*XA[1].y + s1*XA[1].x);
        float2 T2 = make_float2(c2*XA[2].x - s2*XA[2].y, c2*XA[2].y + s2*XA[2].x);
        float2 T3 = make_float2(c3*XA[3].x - s3*XA[3].y, c3*XA[3].y + s3*XA[3].x);
        float2 a = cadd(T0,T2), b = csub(T0,T2), cc = cadd(T1,T3), d = csub(T1,T3);
        Z[0] = cadd(a,cc);
        Z[2] = make_float2(b.x + d.y, b.y - d.x);
        Z[4] = csub(a,cc);
        Z[6] = make_float2(b.x - d.y, b.y + d.x);
    }
    {   // j = sig+256: u_l = w_l * W_8^l; DFT4 -> u = 1,3,5,7
        const float u1x = C8*(c1+s1), u1y = C8*(s1-c1);        // w1 * e^{-i pi/4}
        const float u3x = C8*(s3-c3), u3y = -C8*(s3+c3);       // w3 * e^{-3i pi/4}
        float2 T0 = XB[0];
        float2 T1 = make_float2(u1x*XB[1].x - u1y*XB[1].y, u1x*XB[1].y + u1y*XB[1].x);
        float2 T2 = make_float2(s2*XB[2].x + c2*XB[2].y, s2*XB[2].y - c2*XB[2].x);  // (s2,-c2)*X
        float2 T3 = make_float2(u3x*XB[3].x - u3y*XB[3].y, u3x*XB[3].y + u3y*XB[3].x);
        float2 a = cadd(T0,T2), b = csub(T0,T2), cc = cadd(T1,T3), d = csub(T1,T3);
        Z[1] = cadd(a,cc);
        Z[3] = make_float2(b.x + d.y, b.y - d.x);
        Z[5] = csub(a,cc);
        Z[7] = make_float2(b.x - d.y, b.y + d.x);
    }

    // Untangle via lane-pair swap: Z[2048-k] lives at (partner lane, j'=7-j).
    // Specials: t==0 (sig=0) self-partner j'=(8-j)&7; t==1 (sig=128) j'=7-j.
    // Write raw (y0,y1) back into the SAME phys slots this thread alone read
    // (phys(sig+256j) = po + 288j): race-free, published by the next barrier.
    float2* const Lsig = L + po;
    float s0=0.f, ss0=0.f, sum1=0.f, ss1=0.f;
#pragma unroll
    for (int j = 0; j < 8; ++j) {
        float vx = __shfl_xor(Z[7-j].x, 1, 64);
        float vy = __shfl_xor(Z[7-j].y, 1, 64);
        const int ja = (8-j) & 7;                        // static per unrolled j
        float ax = (t == 0) ? Z[ja].x : Z[7-j].x;
        float ay = (t == 0) ? Z[ja].y : Z[7-j].y;
        vx = (t < 2) ? ax : vx;
        vy = (t < 2) ? ay : vy;
        float a = 0.5f*(Z[j].x + vx);
        float b = 0.5f*(Z[j].y + vy);
        Lsig[288*j] = make_float2(a, b);
        s0+=a; ss0+=a*a; sum1+=b; ss1+=b*b;
    }

    // Wave-64 shuffle reduce, then cross-wave partials via rmem.
#pragma unroll
    for (int off = 32; off > 0; off >>= 1) {
        s0   += __shfl_down(s0,   off, 64);
        ss0  += __shfl_down(ss0,  off, 64);
        sum1 += __shfl_down(sum1, off, 64);
        ss1  += __shfl_down(ss1,  off, 64);
    }
    if ((t & 63) == 0) {
        rmem[4*w+0]=s0; rmem[4*w+1]=ss0; rmem[4*w+2]=sum1; rmem[4*w+3]=ss1;
    }
    __syncthreads();   // barrier #2: publishes rmem AND the y-values in L

    // Coalesced gamma/beta (float4); issued first to hide L2 latency.
    const float4 g0 = ((const float4*)gamma)[t];
    const float4 b0 = ((const float4*)beta )[t];
    const float4 g1 = ((const float4*)gamma)[t + 256];
    const float4 b1 = ((const float4*)beta )[t + 256];

    float S0=0.f, SS0=0.f, S1=0.f, SS1=0.f;
#pragma unroll
    for (int v = 0; v < 4; ++v) {
        S0+=rmem[4*v+0]; SS0+=rmem[4*v+1]; S1+=rmem[4*v+2]; SS1+=rmem[4*v+3];
    }
    const float inv = 1.0f/(float)CD;
    const float mu0 = S0*inv, mu1 = S1*inv;
    const float r0 = rsqrtf(SS0*inv - mu0*mu0 + 1e-5f);
    const float r1 = rsqrtf(SS1*inv - mu1*mu1 + 1e-5f);

    // Repartitioned epilogue: thread t handles CONTIGUOUS k in [4t,4t+4) and
    // [1024+4t, 1024+4t+4). phys(4t+1024h+c) = 4t+(t>>1) + 1152h + c.
    const float2* const Ls = L + (4*t + (t >> 1));
    float4* __restrict__ o0 = (float4*)(out + row0*CD);
    float4* __restrict__ o1 = (float4*)(out + (row0+1)*CD);
#pragma unroll
    for (int h = 0; h < 2; ++h) {
        float2 p0 = Ls[1152*h + 0];
        float2 p1 = Ls[1152*h + 1];
        float2 p2 = Ls[1152*h + 2];
        float2 p3 = Ls[1152*h + 3];
        const float4 g  = h ? g1 : g0;
        const float4 be = h ? b1 : b0;
        float4 v0, v1;
        v0.x=(p0.x-mu0)*r0*g.x+be.x; v1.x=(p0.y-mu1)*r1*g.x+be.x;
        v0.y=(p1.x-mu0)*r0*g.y+be.y; v1.y=(p1.y-mu1)*r1*g.y+be.y;
        v0.z=(p2.x-mu0)*r0*g.z+be.z; v1.z=(p2.y-mu1)*r1*g.z+be.z;
        v0.w=(p3.x-mu0)*r0*g.w+be.w; v1.w=(p3.y-mu1)*r1*g.w+be.w;
        o0[t + 256*h] = v0;
        o1[t + 256*h] = v1;
    }
}

extern "C" void kernel_launch(void* const* d_in, const int* in_sizes, int n_in,
                              void* d_out, int out_size, void* d_ws, size_t ws_size,
                              hipStream_t stream) {
    (void)in_sizes; (void)n_in; (void)d_ws; (void)ws_size; (void)out_size;
    const float* x     = (const float*)d_in[0];
    const float* gamma = (const float*)d_in[1];
    const float* beta  = (const float*)d_in[2];
    float* out = (float*)d_out;

    const int total_rows = 4 * 4096;           // B * N
    const int blocks = total_rows / 2;         // one block per row pair
    fourier_ln_kernel<<<blocks, TPB, 0, stream>>>(x, gamma, beta, out);
}